// Round 1
// baseline (6869.543 us; speedup 1.0000x reference)
//
#include <hip/hip_runtime.h>
#include <math.h>

#define N_NODES 50000
#define FEA 64
#define DEG 16
#define HID 256
#define NCLS 16
#define NP0 1351
#define NP1 37
#define EPSV 1e-5f

// ---------------- BatchNorm ----------------
__global__ __launch_bounds__(256) void bn_reduce(const float* __restrict__ x,
                                                 float* __restrict__ bnsum, float* __restrict__ bnsq) {
    __shared__ float s1[256], s2[256];
    int tid = threadIdx.x;
    int f = tid & 63, sub = tid >> 6;
    float a = 0.f, b = 0.f;
    for (int r = blockIdx.x * 4 + sub; r < N_NODES; r += gridDim.x * 4) {
        float v = x[r * FEA + f];
        a += v; b += v * v;
    }
    s1[tid] = a; s2[tid] = b;
    __syncthreads();
    if (tid < 64) {
        a = s1[tid] + s1[tid + 64] + s1[tid + 128] + s1[tid + 192];
        b = s2[tid] + s2[tid + 64] + s2[tid + 128] + s2[tid + 192];
        atomicAdd(&bnsum[tid], a);
        atomicAdd(&bnsq[tid], b);
    }
}

__global__ __launch_bounds__(256) void bn_apply(const float* __restrict__ x,
                                                const float* __restrict__ bnsum, const float* __restrict__ bnsq,
                                                const float* __restrict__ gamma, const float* __restrict__ beta,
                                                float* __restrict__ x0) {
    int gid = blockIdx.x * 256 + threadIdx.x;
    if (gid >= N_NODES * FEA) return;
    int f = gid & 63;
    float mu = bnsum[f] * (1.0f / N_NODES);
    float var = bnsq[f] * (1.0f / N_NODES) - mu * mu;
    float sc = gamma[f] / sqrtf(var + EPSV);
    x0[gid] = (x[gid] - mu) * sc + beta[f];
}

// ---------------- G = C0 . W0^T  (so h_i . C0_j = x_i . G_j), plus ||C0_j||^2 ----------------
__global__ void compute_G(const float* __restrict__ W0, const float* __restrict__ C0,
                          float* __restrict__ G, float* __restrict__ c0n) {
    int j = blockIdx.x, k = threadIdx.x;           // 1351 blocks x 64 threads
    const float* c = C0 + j * HID;
    const float* w = W0 + k * HID;
    float acc = 0.f;
    for (int m = 0; m < HID; ++m) acc += w[m] * c[m];
    G[j * FEA + k] = acc;
    float cn = 0.f;
    for (int m = k; m < HID; m += 64) { float v = c[m]; cn += v * v; }
    for (int off = 32; off; off >>= 1) cn += __shfl_xor(cn, off);
    if (k == 0) c0n[j] = cn;
}

__global__ void cnorm(const float* __restrict__ C, float* __restrict__ cn) {
    int j = blockIdx.x, k = threadIdx.x;           // 37 blocks x 64 threads
    const float* c = C + j * HID;
    float s = 0.f;
    for (int m = k; m < HID; m += 64) { float v = c[m]; s += v * v; }
    for (int off = 32; off; off >>= 1) s += __shfl_xor(s, off);
    if (k == 0) cn[j] = s;
}

// ---------------- level-0 argmin + pooling (atomics) ----------------
__global__ __launch_bounds__(256) void argmin0_pool(const float* __restrict__ xcov,
                                                    const float* __restrict__ G, const float* __restrict__ c0n,
                                                    int* __restrict__ a0, float* __restrict__ cnt0,
                                                    float* __restrict__ p0sum) {
    int i = blockIdx.x * 256 + threadIdx.x;
    if (i >= N_NODES) return;
    float4 xr[16];
    const float4* xp = (const float4*)(xcov + (size_t)i * FEA);
    #pragma unroll
    for (int q = 0; q < 16; ++q) xr[q] = xp[q];
    float best = 3.4e38f; int bj = 0;
    for (int j = 0; j < NP0; ++j) {
        const float4* g = (const float4*)(G + j * FEA);   // wave-uniform -> scalar loads
        float d0 = 0.f, d1 = 0.f, d2 = 0.f, d3 = 0.f;
        #pragma unroll
        for (int q = 0; q < 16; q += 4) {
            float4 g0 = g[q], g1 = g[q+1], g2 = g[q+2], g3 = g[q+3];
            d0 += xr[q].x*g0.x + xr[q].y*g0.y + xr[q].z*g0.z + xr[q].w*g0.w;
            d1 += xr[q+1].x*g1.x + xr[q+1].y*g1.y + xr[q+1].z*g1.z + xr[q+1].w*g1.w;
            d2 += xr[q+2].x*g2.x + xr[q+2].y*g2.y + xr[q+2].z*g2.z + xr[q+2].w*g2.w;
            d3 += xr[q+3].x*g3.x + xr[q+3].y*g3.y + xr[q+3].z*g3.z + xr[q+3].w*g3.w;
        }
        float d = c0n[j] - 2.0f * ((d0 + d1) + (d2 + d3));
        if (d < best) { best = d; bj = j; }     // strict < : first-min, matches argmin
    }
    a0[i] = bj;
    atomicAdd(&cnt0[bj], 1.0f);
    float* ps = p0sum + (size_t)bj * FEA;
    #pragma unroll
    for (int q = 0; q < 16; ++q) {
        atomicAdd(&ps[4*q+0], xr[q].x); atomicAdd(&ps[4*q+1], xr[q].y);
        atomicAdd(&ps[4*q+2], xr[q].z); atomicAdd(&ps[4*q+3], xr[q].w);
    }
}

__global__ void pool_fin(float* __restrict__ psum, const float* __restrict__ cnt, int total) {
    int gid = blockIdx.x * 256 + threadIdx.x;
    if (gid < total) psum[gid] = psum[gid] / fmaxf(cnt[gid >> 6], 1.0f);
}

// ---------------- level-1: h1 = p0 @ W1, argmin vs C1, pool p0 -> p1 ----------------
__global__ __launch_bounds__(64) void level1(const float* __restrict__ p0, const float* __restrict__ W1,
                                             const float* __restrict__ C1, const float* __restrict__ c1n,
                                             int* __restrict__ a1, float* __restrict__ cnt1,
                                             float* __restrict__ p1sum) {
    int i = blockIdx.x;          // 1351 blocks, one wave each
    int lane = threadIdx.x;
    const float* pr = p0 + (size_t)i * FEA;
    float h[4] = {0.f, 0.f, 0.f, 0.f};
    for (int k = 0; k < FEA; ++k) {
        float pv = pr[k];                         // wave-uniform
        #pragma unroll
        for (int q = 0; q < 4; ++q) h[q] += pv * W1[k * HID + q * 64 + lane];
    }
    float hh = h[0]*h[0] + h[1]*h[1] + h[2]*h[2] + h[3]*h[3];
    for (int off = 32; off; off >>= 1) hh += __shfl_xor(hh, off);
    float best = 3.4e38f; int bj = 0;
    for (int j = 0; j < NP1; ++j) {
        const float* cj = C1 + j * HID;
        float dp = h[0]*cj[lane] + h[1]*cj[64+lane] + h[2]*cj[128+lane] + h[3]*cj[192+lane];
        for (int off = 32; off; off >>= 1) dp += __shfl_xor(dp, off);
        float d = hh - 2.0f * dp + c1n[j];
        if (d < best) { best = d; bj = j; }
    }
    if (lane == 0) { a1[i] = bj; atomicAdd(&cnt1[bj], 1.0f); }
    atomicAdd(&p1sum[bj * FEA + lane], pr[lane]);
}

// ---------------- level-2 (N2=1 => a2==0): p2 = mean(p1), corr2, g1sq, loss part 2 ----------------
__global__ __launch_bounds__(256) void level2(const float* __restrict__ p1, const float* __restrict__ fc,
                                              float* __restrict__ corr2, float* __restrict__ g1sq,
                                              float* __restrict__ loss2f) {
    __shared__ float p2s[64];
    __shared__ float lacc[64];
    int tid = threadIdx.x;
    if (tid < 64) {
        float s = 0.f;
        for (int i = 0; i < NP1; ++i) s += p1[i * FEA + tid];
        p2s[tid] = s * (1.0f / NP1);
        lacc[tid] = 0.f;
    }
    __syncthreads();
    for (int t = tid; t < NP1 * FEA; t += 256) {
        int f = t & 63;
        float dv = p1[t] - p2s[f];
        float c2 = dv * dv;
        corr2[t] = c2;
        float sg = 2.0f / (1.0f + __expf(-(fc[f] - c2)));
        g1sq[t] = sg * sg;
        atomicAdd(&lacc[f], c2);
    }
    __syncthreads();
    if (tid < 64) loss2f[tid] = lacc[tid] * (1.0f / NP1);
}

// ---------------- corr1, g0sq, loss part 1 ----------------
__global__ __launch_bounds__(256) void corr1_g0(const float* __restrict__ p0, const float* __restrict__ p1,
                                                const int* __restrict__ a1, const float* __restrict__ corr2,
                                                float* __restrict__ g0sq, float* __restrict__ loss1g) {
    __shared__ float sh[256];
    int tid = threadIdx.x;
    int f = tid & 63, sub = tid >> 6;
    int i = blockIdx.x * 4 + sub;
    float c1v = 0.f;
    if (i < NP0) {
        int a = a1[i];
        float dv = p0[i * FEA + f] - p1[a * FEA + f];
        c1v = dv * dv;
        float sg = 2.0f / (1.0f + __expf(-(corr2[a * FEA + f] - c1v)));
        g0sq[i * FEA + f] = sg * sg;
    }
    sh[tid] = c1v;
    __syncthreads();
    if (tid < 64) atomicAdd(&loss1g[tid], sh[tid] + sh[tid+64] + sh[tid+128] + sh[tid+192]);
}

__global__ void loss_final(const float* __restrict__ loss1g, const float* __restrict__ loss2f,
                           float* __restrict__ out_loss) {
    int lane = threadIdx.x;
    float v = loss1g[lane] * (1.0f / NP0) + loss2f[lane];
    for (int off = 32; off; off >>= 1) v += __shfl_xor(v, off);
    if (lane == 0) out_loss[0] = v * (1.0f / FEA) * 0.5f;   // /(NPOOL-1)
}

__global__ void cl1map(const int* __restrict__ a0, const int* __restrict__ a1, int* __restrict__ cl1) {
    int i = blockIdx.x * 256 + threadIdx.x;
    if (i < N_NODES) cl1[i] = a1[a0[i]];
}

// ---------------- fused per-row softmax + propagation, one wave per row ----------------
__global__ __launch_bounds__(256) void prop(const float* __restrict__ xin, const float* __restrict__ x0,
                                            const int* __restrict__ cols, const float* __restrict__ avals,
                                            const int* __restrict__ cl0, const int* __restrict__ cl1,
                                            const float* __restrict__ g0sq, const float* __restrict__ g1sq,
                                            float* __restrict__ xout) {
    int lane = threadIdx.x & 63;
    int i = blockIdx.x * 4 + __builtin_amdgcn_readfirstlane(threadIdx.x >> 6);
    int s0 = cl0[i], s1 = cl1[i];
    float g0f = g0sq[s0 * FEA + lane];
    float g1f = g1sq[s1 * FEA + lane];
    float x0f = x0[(size_t)i * FEA + lane];
    int ce[DEG]; float v[DEG];
    float m = -3.4e38f;
    #pragma unroll
    for (int e = 0; e < DEG; ++e) {
        int c = cols[i * DEG + e];
        ce[e] = c;
        float val = avals[i * DEG + e];
        if (cl0[c] == s0) val += g0f;
        if (cl1[c] == s1) val += g1f;
        v[e] = val;
        m = fmaxf(m, val);
    }
    float se = 0.f, acc = 0.f;
    #pragma unroll
    for (int e = 0; e < DEG; ++e) {
        float w = __expf(v[e] - m);
        se += w;
        acc += w * xin[(size_t)ce[e] * FEA + lane];
    }
    xout[(size_t)i * FEA + lane] = acc / se + x0f;   // ALPHA = 1
}

// ---------------- MLP layer 1: [x || x0] (K=128) @ mW1 + b, PReLU ----------------
__global__ __launch_bounds__(256) void mlp1(const float* __restrict__ xp, const float* __restrict__ x0,
                                            const float* __restrict__ W, const float* __restrict__ b,
                                            const float* __restrict__ pp, float* __restrict__ hout) {
    __shared__ float As[64 * 129];
    int bid = blockIdx.x;
    int rb = bid >> 2, cb = bid & 3;
    int row0 = rb * 64;
    int tid = threadIdx.x;
    for (int idx = tid; idx < 64 * 128; idx += 256) {
        int r = idx >> 7, k = idx & 127;
        int row = row0 + r;
        float vv = 0.f;
        if (row < N_NODES) vv = (k < 64) ? xp[(size_t)row * FEA + k] : x0[(size_t)row * FEA + (k - 64)];
        As[r * 129 + k] = vv;
    }
    __syncthreads();
    int r = tid & 63;
    int g = __builtin_amdgcn_readfirstlane(tid >> 6);
    int col0 = cb * 64 + g * 16;
    float acc[16];
    #pragma unroll
    for (int c = 0; c < 16; ++c) acc[c] = 0.f;
    for (int k = 0; k < 128; ++k) {
        float a = As[r * 129 + k];
        const float* w = W + k * HID + col0;   // wave-uniform -> scalar loads
        #pragma unroll
        for (int c = 0; c < 16; ++c) acc[c] += a * w[c];
    }
    int row = row0 + r;
    if (row < N_NODES) {
        float p = pp[0];
        float* o = hout + (size_t)row * HID + col0;
        #pragma unroll
        for (int c = 0; c < 16; ++c) {
            float h = acc[c] + b[col0 + c];
            o[c] = h >= 0.f ? h : p * h;
        }
    }
}

// ---------------- MLP layer 2: h1 (K=256) @ mW2 + b, PReLU ----------------
__global__ __launch_bounds__(256) void mlp2(const float* __restrict__ hin, const float* __restrict__ W,
                                            const float* __restrict__ b, const float* __restrict__ pp,
                                            float* __restrict__ hout) {
    __shared__ float As[64 * 129];
    int bid = blockIdx.x;
    int rb = bid >> 2, cb = bid & 3;
    int row0 = rb * 64;
    int tid = threadIdx.x;
    int r = tid & 63;
    int g = __builtin_amdgcn_readfirstlane(tid >> 6);
    int col0 = cb * 64 + g * 16;
    float acc[16];
    #pragma unroll
    for (int c = 0; c < 16; ++c) acc[c] = 0.f;
    for (int half = 0; half < 2; ++half) {
        __syncthreads();
        for (int idx = tid; idx < 64 * 128; idx += 256) {
            int rr = idx >> 7, k = idx & 127;
            int row = row0 + rr;
            As[rr * 129 + k] = (row < N_NODES) ? hin[(size_t)row * HID + half * 128 + k] : 0.f;
        }
        __syncthreads();
        for (int k = 0; k < 128; ++k) {
            float a = As[r * 129 + k];
            const float* w = W + (half * 128 + k) * HID + col0;
            #pragma unroll
            for (int c = 0; c < 16; ++c) acc[c] += a * w[c];
        }
    }
    int row = row0 + r;
    if (row < N_NODES) {
        float p = pp[0];
        float* o = hout + (size_t)row * HID + col0;
        #pragma unroll
        for (int c = 0; c < 16; ++c) {
            float h = acc[c] + b[col0 + c];
            o[c] = h >= 0.f ? h : p * h;
        }
    }
}

// ---------------- MLP layer 3 + log_softmax; lane = (row_sub, class) ----------------
__global__ __launch_bounds__(256) void mlp3(const float* __restrict__ hin, const float* __restrict__ W3,
                                            const float* __restrict__ b3, float* __restrict__ out) {
    __shared__ float Ws[HID * NCLS];
    int tid = threadIdx.x;
    for (int t = tid; t < HID * NCLS; t += 256) Ws[t] = W3[t];
    __syncthreads();
    int lane = tid & 63;
    int wv = __builtin_amdgcn_readfirstlane(tid >> 6);
    int rs = lane >> 4, c = lane & 15;
    int row = blockIdx.x * 16 + wv * 4 + rs;    // 3125 blocks * 16 rows = 50000 exactly
    const float4* hr = (const float4*)(hin + (size_t)row * HID);
    float acc = b3[c];
    for (int k4 = 0; k4 < 64; ++k4) {
        float4 h = hr[k4];
        int k = k4 * 4;
        acc += h.x * Ws[k * NCLS + c];
        acc += h.y * Ws[(k + 1) * NCLS + c];
        acc += h.z * Ws[(k + 2) * NCLS + c];
        acc += h.w * Ws[(k + 3) * NCLS + c];
    }
    float m = acc;
    #pragma unroll
    for (int off = 1; off < 16; off <<= 1) m = fmaxf(m, __shfl_xor(m, off));
    float e = __expf(acc - m);
    float s = e;
    #pragma unroll
    for (int off = 1; off < 16; off <<= 1) s += __shfl_xor(s, off);
    out[(size_t)row * NCLS + c] = acc - m - __logf(s);
}

extern "C" void kernel_launch(void* const* d_in, const int* in_sizes, int n_in,
                              void* d_out, int out_size, void* d_ws, size_t ws_size,
                              hipStream_t stream) {
    const float* x     = (const float*)d_in[0];
    const float* xcov  = (const float*)d_in[1];
    const float* avals = (const float*)d_in[2];
    const float* fc    = (const float*)d_in[3];
    const float* gamma = (const float*)d_in[4];
    const float* beta  = (const float*)d_in[5];
    const float* W0    = (const float*)d_in[6];
    const float* C0    = (const float*)d_in[7];
    const float* W1    = (const float*)d_in[8];
    const float* C1    = (const float*)d_in[9];
    // d_in[10], d_in[11] (W2, C2) only affect a2, which is argmin over 1 cluster -> always 0. Unused.
    const float* mW1   = (const float*)d_in[12];
    const float* mb1   = (const float*)d_in[13];
    const float* mp1   = (const float*)d_in[14];
    const float* mW2   = (const float*)d_in[15];
    const float* mb2   = (const float*)d_in[16];
    const float* mp2   = (const float*)d_in[17];
    const float* mW3   = (const float*)d_in[18];
    const float* mb3   = (const float*)d_in[19];
    // d_in[20] adj_rows == repeat(arange(N), 16) -> row of edge e is e>>4. Unused.
    const int* cols    = (const int*)d_in[21];

    float* ws = (float*)d_ws;
    size_t off = 0;
    auto alloc = [&](size_t n) { float* p = ws + off; off += (n + 63) & ~(size_t)63; return p; };

    float* x0    = alloc((size_t)N_NODES * FEA);
    float* h1b   = alloc((size_t)N_NODES * HID);   // xb1 aliases its head
    float* h2b   = alloc((size_t)N_NODES * HID);   // xb2 aliases its head
    float* G     = alloc(NP0 * FEA);
    float* c0n   = alloc(NP0);
    float* c1n   = alloc(NP1);
    float* g0sq  = alloc(NP0 * FEA);
    float* g1sq  = alloc(NP1 * FEA);
    float* corr2 = alloc(NP1 * FEA);
    float* loss2f= alloc(64);
    int*   a0    = (int*)alloc(N_NODES);
    int*   cl1   = (int*)alloc(N_NODES);
    int*   a1    = (int*)alloc(NP0);
    // ---- zero-initialized block (single memset) ----
    float* zero0 = ws + off;
    float* bnsum = alloc(64);
    float* bnsq  = alloc(64);
    float* cnt0  = alloc(NP0);
    float* cnt1  = alloc(NP1);
    float* loss1g= alloc(64);
    float* p0    = alloc(NP0 * FEA);   // accumulated then finalized in place
    float* p1    = alloc(NP1 * FEA);
    size_t zbytes = (size_t)((ws + off) - zero0) * sizeof(float);

    float* xb1 = h1b;
    float* xb2 = h2b;
    float* outp = (float*)d_out;

    hipMemsetAsync(zero0, 0, zbytes, stream);

    bn_reduce<<<256, 256, 0, stream>>>(x, bnsum, bnsq);
    bn_apply<<<(N_NODES * FEA) / 256, 256, 0, stream>>>(x, bnsum, bnsq, gamma, beta, x0);

    compute_G<<<NP0, 64, 0, stream>>>(W0, C0, G, c0n);
    cnorm<<<NP1, 64, 0, stream>>>(C1, c1n);

    argmin0_pool<<<(N_NODES + 255) / 256, 256, 0, stream>>>(xcov, G, c0n, a0, cnt0, p0);
    pool_fin<<<(NP0 * FEA + 255) / 256, 256, 0, stream>>>(p0, cnt0, NP0 * FEA);

    level1<<<NP0, 64, 0, stream>>>(p0, W1, C1, c1n, a1, cnt1, p1);
    pool_fin<<<(NP1 * FEA + 255) / 256, 256, 0, stream>>>(p1, cnt1, NP1 * FEA);

    level2<<<1, 256, 0, stream>>>(p1, fc, corr2, g1sq, loss2f);
    corr1_g0<<<(NP0 + 3) / 4, 256, 0, stream>>>(p0, p1, a1, corr2, g0sq, loss1g);
    loss_final<<<1, 64, 0, stream>>>(loss1g, loss2f, outp + (size_t)N_NODES * NCLS);

    cl1map<<<(N_NODES + 255) / 256, 256, 0, stream>>>(a0, a1, cl1);

    prop<<<N_NODES / 4, 256, 0, stream>>>(x0, x0, cols, avals, a0, cl1, g0sq, g1sq, xb1);
    prop<<<N_NODES / 4, 256, 0, stream>>>(xb1, x0, cols, avals, a0, cl1, g0sq, g1sq, xb2);

    int rowBlocks = (N_NODES + 63) / 64;
    mlp1<<<rowBlocks * 4, 256, 0, stream>>>(xb2, x0, mW1, mb1, mp1, h1b);
    mlp2<<<rowBlocks * 4, 256, 0, stream>>>(h1b, mW2, mb2, mp2, h2b);
    mlp3<<<N_NODES / 16, 256, 0, stream>>>(h2b, mW3, mb3, outp);
}

// Round 2
// 1290.429 us; speedup vs baseline: 5.3235x; 5.3235x over previous
//
#include <hip/hip_runtime.h>
#include <math.h>

#define N_NODES 50000
#define FEA 64
#define DEG 16
#define HID 256
#define NCLS 16
#define NP0 1351
#define NP1 37
#define EPSV 1e-5f
#define NCHUNK 4
#define CHSZ 338   // ceil(1351/4)

// ---------------- BatchNorm ----------------
__global__ __launch_bounds__(256) void bn_reduce(const float* __restrict__ x,
                                                 float* __restrict__ bnsum, float* __restrict__ bnsq) {
    __shared__ float s1[256], s2[256];
    int tid = threadIdx.x;
    int f = tid & 63, sub = tid >> 6;
    float a = 0.f, b = 0.f;
    for (int r = blockIdx.x * 4 + sub; r < N_NODES; r += gridDim.x * 4) {
        float v = x[r * FEA + f];
        a += v; b += v * v;
    }
    s1[tid] = a; s2[tid] = b;
    __syncthreads();
    if (tid < 64) {
        a = s1[tid] + s1[tid + 64] + s1[tid + 128] + s1[tid + 192];
        b = s2[tid] + s2[tid + 64] + s2[tid + 128] + s2[tid + 192];
        atomicAdd(&bnsum[tid], a);
        atomicAdd(&bnsq[tid], b);
    }
}

__global__ __launch_bounds__(256) void bn_apply(const float* __restrict__ x,
                                                const float* __restrict__ bnsum, const float* __restrict__ bnsq,
                                                const float* __restrict__ gamma, const float* __restrict__ beta,
                                                float* __restrict__ x0) {
    int gid = blockIdx.x * 256 + threadIdx.x;
    if (gid >= N_NODES * FEA) return;
    int f = gid & 63;
    float mu = bnsum[f] * (1.0f / N_NODES);
    float var = bnsq[f] * (1.0f / N_NODES) - mu * mu;
    float sc = gamma[f] / sqrtf(var + EPSV);
    x0[gid] = (x[gid] - mu) * sc + beta[f];
}

// ---------------- G = C0 . W0^T  (so h_i . C0_j = x_i . G_j), plus ||C0_j||^2 ----------------
__global__ void compute_G(const float* __restrict__ W0, const float* __restrict__ C0,
                          float* __restrict__ G, float* __restrict__ c0n) {
    int j = blockIdx.x, k = threadIdx.x;           // 1351 blocks x 64 threads
    const float* c = C0 + j * HID;
    const float* w = W0 + k * HID;
    float acc = 0.f;
    for (int m = 0; m < HID; ++m) acc += w[m] * c[m];
    G[j * FEA + k] = acc;
    float cn = 0.f;
    for (int m = k; m < HID; m += 64) { float v = c[m]; cn += v * v; }
    for (int off = 32; off; off >>= 1) cn += __shfl_xor(cn, off);
    if (k == 0) c0n[j] = cn;
}

__global__ void cnorm(const float* __restrict__ C, float* __restrict__ cn) {
    int j = blockIdx.x, k = threadIdx.x;           // 37 blocks x 64 threads
    const float* c = C + j * HID;
    float s = 0.f;
    for (int m = k; m < 64; ) { break; }           // (unused path guard, no-op)
    float acc = 0.f;
    for (int m = k; m < HID; m += 64) { float v = c[m]; acc += v * v; }
    for (int off = 32; off; off >>= 1) acc += __shfl_xor(acc, off);
    if (k == 0) cn[j] = acc;
}

// ---------------- level-0 argmin: one wave per 64 rows, clusters split in 4 chunks ----------------
// best over chunk merged via atomicMin on packed (ordered_dist << 32 | j): first-min semantics.
__global__ __launch_bounds__(64, 3) void argmin0_dist(const float* __restrict__ xcov,
                                                      const float* __restrict__ G,
                                                      const float* __restrict__ c0n,
                                                      unsigned long long* __restrict__ amin) {
    int i = (blockIdx.x >> 2) * 64 + threadIdx.x;   // row
    int chunk = blockIdx.x & 3;
    if (i >= N_NODES) return;
    int j0 = chunk * CHSZ;
    int j1 = j0 + CHSZ; if (j1 > NP0) j1 = NP0;

    float4 xr[16];
    const float4* xp = (const float4*)(xcov + (size_t)i * FEA);
    #pragma unroll
    for (int q = 0; q < 16; ++q) xr[q] = xp[q];

    float best = 3.4e38f; int bj = j0;
    float4 gc[16];
    {
        const float4* gp = (const float4*)(G + (size_t)j0 * FEA);
        #pragma unroll
        for (int q = 0; q < 16; ++q) gc[q] = gp[q];
    }
    for (int j = j0; j < j1; ++j) {
        // prefetch next row of G (wave-uniform address) while computing current
        int jn = j + 1; if (jn >= j1) jn = j1 - 1;
        const float4* gq = (const float4*)(G + (size_t)jn * FEA);
        float4 gn[16];
        #pragma unroll
        for (int q = 0; q < 16; ++q) gn[q] = gq[q];

        float d0 = 0.f, d1 = 0.f, d2 = 0.f, d3 = 0.f;
        #pragma unroll
        for (int q = 0; q < 16; q += 4) {
            d0 += xr[q].x*gc[q].x + xr[q].y*gc[q].y + xr[q].z*gc[q].z + xr[q].w*gc[q].w;
            d1 += xr[q+1].x*gc[q+1].x + xr[q+1].y*gc[q+1].y + xr[q+1].z*gc[q+1].z + xr[q+1].w*gc[q+1].w;
            d2 += xr[q+2].x*gc[q+2].x + xr[q+2].y*gc[q+2].y + xr[q+2].z*gc[q+2].z + xr[q+2].w*gc[q+2].w;
            d3 += xr[q+3].x*gc[q+3].x + xr[q+3].y*gc[q+3].y + xr[q+3].z*gc[q+3].z + xr[q+3].w*gc[q+3].w;
        }
        float d = c0n[j] - 2.0f * ((d0 + d1) + (d2 + d3));
        if (d < best) { best = d; bj = j; }     // strict <: first-min within chunk
        #pragma unroll
        for (int q = 0; q < 16; ++q) gc[q] = gn[q];
    }
    unsigned s = __float_as_uint(best);
    unsigned u = ((int)s < 0) ? ~s : (s | 0x80000000u);   // monotone float->uint map
    unsigned long long packed = ((unsigned long long)u << 32) | (unsigned)bj;
    atomicMin(&amin[i], packed);
}

// ---------------- extract a0 + pooling atomics ----------------
__global__ __launch_bounds__(256) void pool0(const unsigned long long* __restrict__ amin,
                                             const float* __restrict__ xcov, int* __restrict__ a0,
                                             float* __restrict__ cnt0, float* __restrict__ p0sum) {
    int lane = threadIdx.x & 63;
    int i = blockIdx.x * 4 + (threadIdx.x >> 6);
    if (i >= N_NODES) return;
    int j = (int)(unsigned)amin[i];
    if (lane == 0) { a0[i] = j; atomicAdd(&cnt0[j], 1.0f); }
    atomicAdd(&p0sum[j * FEA + lane], xcov[(size_t)i * FEA + lane]);
}

__global__ void pool_fin(float* __restrict__ psum, const float* __restrict__ cnt, int total) {
    int gid = blockIdx.x * 256 + threadIdx.x;
    if (gid < total) psum[gid] = psum[gid] / fmaxf(cnt[gid >> 6], 1.0f);
}

// ---------------- level-1: h1 = p0 @ W1, argmin vs C1, pool p0 -> p1 ----------------
__global__ __launch_bounds__(64) void level1(const float* __restrict__ p0, const float* __restrict__ W1,
                                             const float* __restrict__ C1, const float* __restrict__ c1n,
                                             int* __restrict__ a1, float* __restrict__ cnt1,
                                             float* __restrict__ p1sum) {
    int i = blockIdx.x;          // 1351 blocks, one wave each
    int lane = threadIdx.x;
    const float* pr = p0 + (size_t)i * FEA;
    float h[4] = {0.f, 0.f, 0.f, 0.f};
    for (int k = 0; k < FEA; ++k) {
        float pv = pr[k];                         // wave-uniform
        #pragma unroll
        for (int q = 0; q < 4; ++q) h[q] += pv * W1[k * HID + q * 64 + lane];
    }
    float hh = h[0]*h[0] + h[1]*h[1] + h[2]*h[2] + h[3]*h[3];
    for (int off = 32; off; off >>= 1) hh += __shfl_xor(hh, off);
    float best = 3.4e38f; int bj = 0;
    for (int j = 0; j < NP1; ++j) {
        const float* cj = C1 + j * HID;
        float dp = h[0]*cj[lane] + h[1]*cj[64+lane] + h[2]*cj[128+lane] + h[3]*cj[192+lane];
        for (int off = 32; off; off >>= 1) dp += __shfl_xor(dp, off);
        float d = hh - 2.0f * dp + c1n[j];
        if (d < best) { best = d; bj = j; }
    }
    if (lane == 0) { a1[i] = bj; atomicAdd(&cnt1[bj], 1.0f); }
    atomicAdd(&p1sum[bj * FEA + lane], pr[lane]);
}

// ---------------- level-2 (N2=1 => a2==0): p2 = mean(p1), corr2, g1sq, loss part 2 ----------------
__global__ __launch_bounds__(256) void level2(const float* __restrict__ p1, const float* __restrict__ fc,
                                              float* __restrict__ corr2, float* __restrict__ g1sq,
                                              float* __restrict__ loss2f) {
    __shared__ float p2s[64];
    __shared__ float lacc[64];
    int tid = threadIdx.x;
    if (tid < 64) {
        float s = 0.f;
        for (int i = 0; i < NP1; ++i) s += p1[i * FEA + tid];
        p2s[tid] = s * (1.0f / NP1);
        lacc[tid] = 0.f;
    }
    __syncthreads();
    for (int t = tid; t < NP1 * FEA; t += 256) {
        int f = t & 63;
        float dv = p1[t] - p2s[f];
        float c2 = dv * dv;
        corr2[t] = c2;
        float sg = 2.0f / (1.0f + __expf(-(fc[f] - c2)));
        g1sq[t] = sg * sg;
        atomicAdd(&lacc[f], c2);
    }
    __syncthreads();
    if (tid < 64) loss2f[tid] = lacc[tid] * (1.0f / NP1);
}

// ---------------- corr1, g0sq, loss part 1 ----------------
__global__ __launch_bounds__(256) void corr1_g0(const float* __restrict__ p0, const float* __restrict__ p1,
                                                const int* __restrict__ a1, const float* __restrict__ corr2,
                                                float* __restrict__ g0sq, float* __restrict__ loss1g) {
    __shared__ float sh[256];
    int tid = threadIdx.x;
    int f = tid & 63, sub = tid >> 6;
    int i = blockIdx.x * 4 + sub;
    float c1v = 0.f;
    if (i < NP0) {
        int a = a1[i];
        float dv = p0[i * FEA + f] - p1[a * FEA + f];
        c1v = dv * dv;
        float sg = 2.0f / (1.0f + __expf(-(corr2[a * FEA + f] - c1v)));
        g0sq[i * FEA + f] = sg * sg;
    }
    sh[tid] = c1v;
    __syncthreads();
    if (tid < 64) atomicAdd(&loss1g[tid], sh[tid] + sh[tid+64] + sh[tid+128] + sh[tid+192]);
}

__global__ void loss_final(const float* __restrict__ loss1g, const float* __restrict__ loss2f,
                           float* __restrict__ out_loss) {
    int lane = threadIdx.x;
    float v = loss1g[lane] * (1.0f / NP0) + loss2f[lane];
    for (int off = 32; off; off >>= 1) v += __shfl_xor(v, off);
    if (lane == 0) out_loss[0] = v * (1.0f / FEA) * 0.5f;   // /(NPOOL-1)
}

__global__ void cl1map(const int* __restrict__ a0, const int* __restrict__ a1, int* __restrict__ cl1) {
    int i = blockIdx.x * 256 + threadIdx.x;
    if (i < N_NODES) cl1[i] = a1[a0[i]];
}

// ---------------- fused per-row softmax + propagation, one wave per row ----------------
__global__ __launch_bounds__(256) void prop(const float* __restrict__ xin, const float* __restrict__ x0,
                                            const int* __restrict__ cols, const float* __restrict__ avals,
                                            const int* __restrict__ cl0, const int* __restrict__ cl1,
                                            const float* __restrict__ g0sq, const float* __restrict__ g1sq,
                                            float* __restrict__ xout) {
    int lane = threadIdx.x & 63;
    int i = blockIdx.x * 4 + __builtin_amdgcn_readfirstlane(threadIdx.x >> 6);
    int s0 = cl0[i], s1 = cl1[i];
    float g0f = g0sq[s0 * FEA + lane];
    float g1f = g1sq[s1 * FEA + lane];
    float x0f = x0[(size_t)i * FEA + lane];
    int ce[DEG]; float v[DEG];
    float m = -3.4e38f;
    #pragma unroll
    for (int e = 0; e < DEG; ++e) {
        int c = cols[i * DEG + e];
        ce[e] = c;
        float val = avals[i * DEG + e];
        if (cl0[c] == s0) val += g0f;
        if (cl1[c] == s1) val += g1f;
        v[e] = val;
        m = fmaxf(m, val);
    }
    float se = 0.f, acc = 0.f;
    #pragma unroll
    for (int e = 0; e < DEG; ++e) {
        float w = __expf(v[e] - m);
        se += w;
        acc += w * xin[(size_t)ce[e] * FEA + lane];
    }
    xout[(size_t)i * FEA + lane] = acc / se + x0f;   // ALPHA = 1
}

// ---------------- MLP layer 1: [x || x0] (K=128) @ mW1 + b, PReLU ----------------
__global__ __launch_bounds__(256) void mlp1(const float* __restrict__ xp, const float* __restrict__ x0,
                                            const float* __restrict__ W, const float* __restrict__ b,
                                            const float* __restrict__ pp, float* __restrict__ hout) {
    __shared__ float As[64 * 129];
    int bid = blockIdx.x;
    int rb = bid >> 2, cb = bid & 3;
    int row0 = rb * 64;
    int tid = threadIdx.x;
    for (int idx = tid; idx < 64 * 128; idx += 256) {
        int r = idx >> 7, k = idx & 127;
        int row = row0 + r;
        float vv = 0.f;
        if (row < N_NODES) vv = (k < 64) ? xp[(size_t)row * FEA + k] : x0[(size_t)row * FEA + (k - 64)];
        As[r * 129 + k] = vv;
    }
    __syncthreads();
    int r = tid & 63;
    int g = __builtin_amdgcn_readfirstlane(tid >> 6);
    int col0 = cb * 64 + g * 16;
    float acc[16];
    #pragma unroll
    for (int c = 0; c < 16; ++c) acc[c] = 0.f;
    for (int k = 0; k < 128; ++k) {
        float a = As[r * 129 + k];
        const float* w = W + k * HID + col0;   // wave-uniform -> scalar loads
        #pragma unroll
        for (int c = 0; c < 16; ++c) acc[c] += a * w[c];
    }
    int row = row0 + r;
    if (row < N_NODES) {
        float p = pp[0];
        float* o = hout + (size_t)row * HID + col0;
        #pragma unroll
        for (int c = 0; c < 16; ++c) {
            float h = acc[c] + b[col0 + c];
            o[c] = h >= 0.f ? h : p * h;
        }
    }
}

// ---------------- MLP layer 2: h1 (K=256) @ mW2 + b, PReLU ----------------
__global__ __launch_bounds__(256) void mlp2(const float* __restrict__ hin, const float* __restrict__ W,
                                            const float* __restrict__ b, const float* __restrict__ pp,
                                            float* __restrict__ hout) {
    __shared__ float As[64 * 129];
    int bid = blockIdx.x;
    int rb = bid >> 2, cb = bid & 3;
    int row0 = rb * 64;
    int tid = threadIdx.x;
    int r = tid & 63;
    int g = __builtin_amdgcn_readfirstlane(tid >> 6);
    int col0 = cb * 64 + g * 16;
    float acc[16];
    #pragma unroll
    for (int c = 0; c < 16; ++c) acc[c] = 0.f;
    for (int half = 0; half < 2; ++half) {
        __syncthreads();
        for (int idx = tid; idx < 64 * 128; idx += 256) {
            int rr = idx >> 7, k = idx & 127;
            int row = row0 + rr;
            As[rr * 129 + k] = (row < N_NODES) ? hin[(size_t)row * HID + half * 128 + k] : 0.f;
        }
        __syncthreads();
        for (int k = 0; k < 128; ++k) {
            float a = As[r * 129 + k];
            const float* w = W + (half * 128 + k) * HID + col0;
            #pragma unroll
            for (int c = 0; c < 16; ++c) acc[c] += a * w[c];
        }
    }
    int row = row0 + r;
    if (row < N_NODES) {
        float p = pp[0];
        float* o = hout + (size_t)row * HID + col0;
        #pragma unroll
        for (int c = 0; c < 16; ++c) {
            float h = acc[c] + b[col0 + c];
            o[c] = h >= 0.f ? h : p * h;
        }
    }
}

// ---------------- MLP layer 3 + log_softmax; lane = (row_sub, class) ----------------
__global__ __launch_bounds__(256) void mlp3(const float* __restrict__ hin, const float* __restrict__ W3,
                                            const float* __restrict__ b3, float* __restrict__ out) {
    __shared__ float Ws[HID * NCLS];
    int tid = threadIdx.x;
    for (int t = tid; t < HID * NCLS; t += 256) Ws[t] = W3[t];
    __syncthreads();
    int lane = tid & 63;
    int wv = __builtin_amdgcn_readfirstlane(tid >> 6);
    int rs = lane >> 4, c = lane & 15;
    int row = blockIdx.x * 16 + wv * 4 + rs;    // 3125 blocks * 16 rows = 50000 exactly
    const float4* hr = (const float4*)(hin + (size_t)row * HID);
    float acc = b3[c];
    for (int k4 = 0; k4 < 64; ++k4) {
        float4 h = hr[k4];
        int k = k4 * 4;
        acc += h.x * Ws[k * NCLS + c];
        acc += h.y * Ws[(k + 1) * NCLS + c];
        acc += h.z * Ws[(k + 2) * NCLS + c];
        acc += h.w * Ws[(k + 3) * NCLS + c];
    }
    float m = acc;
    #pragma unroll
    for (int off = 1; off < 16; off <<= 1) m = fmaxf(m, __shfl_xor(m, off));
    float e = __expf(acc - m);
    float s = e;
    #pragma unroll
    for (int off = 1; off < 16; off <<= 1) s += __shfl_xor(s, off);
    out[(size_t)row * NCLS + c] = acc - m - __logf(s);
}

extern "C" void kernel_launch(void* const* d_in, const int* in_sizes, int n_in,
                              void* d_out, int out_size, void* d_ws, size_t ws_size,
                              hipStream_t stream) {
    const float* x     = (const float*)d_in[0];
    const float* xcov  = (const float*)d_in[1];
    const float* avals = (const float*)d_in[2];
    const float* fc    = (const float*)d_in[3];
    const float* gamma = (const float*)d_in[4];
    const float* beta  = (const float*)d_in[5];
    const float* W0    = (const float*)d_in[6];
    const float* C0    = (const float*)d_in[7];
    const float* W1    = (const float*)d_in[8];
    const float* C1    = (const float*)d_in[9];
    // d_in[10], d_in[11] (W2, C2) only affect a2, which is argmin over 1 cluster -> always 0. Unused.
    const float* mW1   = (const float*)d_in[12];
    const float* mb1   = (const float*)d_in[13];
    const float* mp1   = (const float*)d_in[14];
    const float* mW2   = (const float*)d_in[15];
    const float* mb2   = (const float*)d_in[16];
    const float* mp2   = (const float*)d_in[17];
    const float* mW3   = (const float*)d_in[18];
    const float* mb3   = (const float*)d_in[19];
    // d_in[20] adj_rows == repeat(arange(N), 16) -> row of edge e is e>>4. Unused.
    const int* cols    = (const int*)d_in[21];

    float* ws = (float*)d_ws;
    size_t off = 0;
    auto alloc = [&](size_t n) { float* p = ws + off; off += (n + 63) & ~(size_t)63; return p; };

    float* x0    = alloc((size_t)N_NODES * FEA);
    float* h1b   = alloc((size_t)N_NODES * HID);   // xb1 aliases its head
    float* h2b   = alloc((size_t)N_NODES * HID);   // xb2 aliases its head
    float* G     = alloc(NP0 * FEA);
    float* c0n   = alloc(NP0);
    float* c1n   = alloc(NP1);
    float* g0sq  = alloc(NP0 * FEA);
    float* g1sq  = alloc(NP1 * FEA);
    float* corr2 = alloc(NP1 * FEA);
    float* loss2f= alloc(64);
    int*   a0    = (int*)alloc(N_NODES);
    int*   cl1   = (int*)alloc(N_NODES);
    int*   a1    = (int*)alloc(NP0);
    unsigned long long* amin = (unsigned long long*)alloc((size_t)N_NODES * 2);  // 8B-aligned (allocs are 256B-aligned)
    // ---- zero-initialized block (single memset) ----
    float* zero0 = ws + off;
    float* bnsum = alloc(64);
    float* bnsq  = alloc(64);
    float* cnt0  = alloc(NP0);
    float* cnt1  = alloc(NP1);
    float* loss1g= alloc(64);
    float* p0    = alloc(NP0 * FEA);   // accumulated then finalized in place
    float* p1    = alloc(NP1 * FEA);
    size_t zbytes = (size_t)((ws + off) - zero0) * sizeof(float);

    float* xb1 = h1b;
    float* xb2 = h2b;
    float* outp = (float*)d_out;

    hipMemsetAsync(zero0, 0, zbytes, stream);
    hipMemsetAsync(amin, 0xFF, (size_t)N_NODES * 8, stream);   // UINT64_MAX init for atomicMin

    bn_reduce<<<256, 256, 0, stream>>>(x, bnsum, bnsq);
    bn_apply<<<(N_NODES * FEA) / 256, 256, 0, stream>>>(x, bnsum, bnsq, gamma, beta, x0);

    compute_G<<<NP0, 64, 0, stream>>>(W0, C0, G, c0n);
    cnorm<<<NP1, 64, 0, stream>>>(C1, c1n);

    int rowWaves = (N_NODES + 63) / 64;             // 782
    argmin0_dist<<<rowWaves * NCHUNK, 64, 0, stream>>>(xcov, G, c0n, amin);
    pool0<<<(N_NODES + 3) / 4, 256, 0, stream>>>(amin, xcov, a0, cnt0, p0);
    pool_fin<<<(NP0 * FEA + 255) / 256, 256, 0, stream>>>(p0, cnt0, NP0 * FEA);

    level1<<<NP0, 64, 0, stream>>>(p0, W1, C1, c1n, a1, cnt1, p1);
    pool_fin<<<(NP1 * FEA + 255) / 256, 256, 0, stream>>>(p1, cnt1, NP1 * FEA);

    level2<<<1, 256, 0, stream>>>(p1, fc, corr2, g1sq, loss2f);
    corr1_g0<<<(NP0 + 3) / 4, 256, 0, stream>>>(p0, p1, a1, corr2, g0sq, loss1g);
    loss_final<<<1, 64, 0, stream>>>(loss1g, loss2f, outp + (size_t)N_NODES * NCLS);

    cl1map<<<(N_NODES + 255) / 256, 256, 0, stream>>>(a0, a1, cl1);

    prop<<<N_NODES / 4, 256, 0, stream>>>(x0, x0, cols, avals, a0, cl1, g0sq, g1sq, xb1);
    prop<<<N_NODES / 4, 256, 0, stream>>>(xb1, x0, cols, avals, a0, cl1, g0sq, g1sq, xb2);

    int rowBlocks = (N_NODES + 63) / 64;
    mlp1<<<rowBlocks * 4, 256, 0, stream>>>(xb2, x0, mW1, mb1, mp1, h1b);
    mlp2<<<rowBlocks * 4, 256, 0, stream>>>(h1b, mW2, mb2, mp2, h2b);
    mlp3<<<N_NODES / 16, 256, 0, stream>>>(h2b, mW3, mb3, outp);
}

// Round 3
// 1201.372 us; speedup vs baseline: 5.7181x; 1.0741x over previous
//
#include <hip/hip_runtime.h>
#include <math.h>

#define N_NODES 50000
#define FEA 64
#define DEG 16
#define HID 256
#define NCLS 16
#define NP0 1351
#define NP0T 1408   // padded to 22*64
#define NTILE 22
#define NP1 37
#define EPSV 1e-5f

// ---------------- BatchNorm ----------------
__global__ __launch_bounds__(256) void bn_reduce(const float* __restrict__ x,
                                                 float* __restrict__ bnsum, float* __restrict__ bnsq) {
    __shared__ float s1[256], s2[256];
    int tid = threadIdx.x;
    int f = tid & 63, sub = tid >> 6;
    float a = 0.f, b = 0.f;
    for (int r = blockIdx.x * 4 + sub; r < N_NODES; r += gridDim.x * 4) {
        float v = x[r * FEA + f];
        a += v; b += v * v;
    }
    s1[tid] = a; s2[tid] = b;
    __syncthreads();
    if (tid < 64) {
        a = s1[tid] + s1[tid + 64] + s1[tid + 128] + s1[tid + 192];
        b = s2[tid] + s2[tid + 64] + s2[tid + 128] + s2[tid + 192];
        atomicAdd(&bnsum[tid], a);
        atomicAdd(&bnsq[tid], b);
    }
}

__global__ __launch_bounds__(256) void bn_apply(const float* __restrict__ x,
                                                const float* __restrict__ bnsum, const float* __restrict__ bnsq,
                                                const float* __restrict__ gamma, const float* __restrict__ beta,
                                                float* __restrict__ x0) {
    int gid = blockIdx.x * 256 + threadIdx.x;
    if (gid >= N_NODES * FEA) return;
    int f = gid & 63;
    float mu = bnsum[f] * (1.0f / N_NODES);
    float var = bnsq[f] * (1.0f / N_NODES) - mu * mu;
    float sc = gamma[f] / sqrtf(var + EPSV);
    x0[gid] = (x[gid] - mu) * sc + beta[f];
}

// ---------------- W0 transpose (64x256 -> 256x64) for coalesced G build ----------------
__global__ void transpose_W0(const float* __restrict__ W0, float* __restrict__ W0t) {
    int idx = blockIdx.x * 256 + threadIdx.x;
    if (idx < FEA * HID) {
        int f = idx >> 8, h = idx & 255;
        W0t[h * FEA + f] = W0[idx];
    }
}

// ---------------- Gt[k][j] = sum_m W0t[m][k]*C0[j][m]; c0n[j]=||C0_j||^2; pad j>=NP0 ----------------
__global__ __launch_bounds__(64) void compute_G2(const float* __restrict__ W0t, const float* __restrict__ C0,
                                                 float* __restrict__ Gt, float* __restrict__ c0n) {
    int j = blockIdx.x, k = threadIdx.x;           // 1408 blocks x 64 threads
    if (j >= NP0) {
        Gt[k * NP0T + j] = 0.f;
        if (k == 0) c0n[j] = 3.4e38f;
        return;
    }
    const float* c = C0 + j * HID;                 // wave-uniform reads
    float acc = 0.f;
    for (int m = 0; m < HID; ++m) acc += W0t[m * FEA + k] * c[m];   // coalesced over k
    Gt[k * NP0T + j] = acc;
    float cn = 0.f;
    for (int m = k; m < HID; m += 64) { float v = c[m]; cn += v * v; }
    for (int off = 32; off; off >>= 1) cn += __shfl_xor(cn, off);
    if (k == 0) c0n[j] = cn;
}

__global__ void cnorm(const float* __restrict__ C, float* __restrict__ cn) {
    int j = blockIdx.x, k = threadIdx.x;           // 37 blocks x 64 threads
    const float* c = C + j * HID;
    float acc = 0.f;
    for (int m = k; m < HID; m += 64) { float v = c[m]; acc += v * v; }
    for (int off = 32; off; off >>= 1) acc += __shfl_xor(acc, off);
    if (k == 0) cn[j] = acc;
}

// ---------------- level-0: LDS-tiled GEMM + fused argmin + fused pooling ----------------
// Block: 256 thr = 16 row-quads (tr) x 16 col-quads (tc). 64 rows/block, 22 tiles of 64 cols.
// dist = c0n[j] - 2*dot(x_i, G_j); ||h_i||^2 dropped (row-constant). Packed (dist|j) min
// gives first-min tie semantics (== np.argmin).
__global__ __launch_bounds__(256) void argmin0_gemm(const float* __restrict__ xcov,
                                                    const float* __restrict__ Gt,
                                                    const float* __restrict__ c0n,
                                                    int* __restrict__ a0,
                                                    float* __restrict__ cnt0,
                                                    float* __restrict__ p0sum) {
    __shared__ float As[64 * 68];              // As[k][m] = x[row0+m][k], stride 68 (16B-aligned, 2-way banks)
    __shared__ float Bs[64 * 68];              // Bs[k][j] = G[j0+j][k]
    __shared__ float cs[64];
    __shared__ unsigned long long pmin[64 * 16];
    __shared__ int win[64];
    int t = threadIdx.x;
    int row0 = blockIdx.x * 64;

    // stage x transposed: thread loads 16 floats of one row
    {
        int r = t >> 2, part = t & 3;
        int row = row0 + r;
        float4 v0, v1, v2, v3;
        if (row < N_NODES) {
            const float4* xp = (const float4*)(xcov + (size_t)row * FEA + part * 16);
            v0 = xp[0]; v1 = xp[1]; v2 = xp[2]; v3 = xp[3];
        } else {
            v0 = v1 = v2 = v3 = make_float4(0.f, 0.f, 0.f, 0.f);
        }
        int k = part * 16;
        As[(k+0)*68+r]=v0.x;  As[(k+1)*68+r]=v0.y;  As[(k+2)*68+r]=v0.z;  As[(k+3)*68+r]=v0.w;
        As[(k+4)*68+r]=v1.x;  As[(k+5)*68+r]=v1.y;  As[(k+6)*68+r]=v1.z;  As[(k+7)*68+r]=v1.w;
        As[(k+8)*68+r]=v2.x;  As[(k+9)*68+r]=v2.y;  As[(k+10)*68+r]=v2.z; As[(k+11)*68+r]=v2.w;
        As[(k+12)*68+r]=v3.x; As[(k+13)*68+r]=v3.y; As[(k+14)*68+r]=v3.z; As[(k+15)*68+r]=v3.w;
    }

    int tr = t & 15, tc = t >> 4;
    unsigned long long best[4] = {~0ull, ~0ull, ~0ull, ~0ull};   // per local row

    for (int tile = 0; tile < NTILE; ++tile) {
        int j0 = tile * 64;
        __syncthreads();
        // stage G tile: Gt rows are contiguous in j -> coalesced float4 loads
        {
            int k = t >> 2, part = t & 3;
            const float4* gp = (const float4*)(Gt + (size_t)k * NP0T + j0 + part * 16);
            float4 g0 = gp[0], g1 = gp[1], g2 = gp[2], g3 = gp[3];
            float4* bp = (float4*)(Bs + k * 68 + part * 16);
            bp[0] = g0; bp[1] = g1; bp[2] = g2; bp[3] = g3;
        }
        if (t < 64) cs[t] = c0n[j0 + t];
        __syncthreads();

        float acc[4][4];
        #pragma unroll
        for (int r = 0; r < 4; ++r)
            #pragma unroll
            for (int c = 0; c < 4; ++c) acc[r][c] = 0.f;

        #pragma unroll 4
        for (int k = 0; k < 64; ++k) {
            float4 a = *(const float4*)(As + k * 68 + 4 * tr);
            float4 b = *(const float4*)(Bs + k * 68 + 4 * tc);
            acc[0][0]+=a.x*b.x; acc[0][1]+=a.x*b.y; acc[0][2]+=a.x*b.z; acc[0][3]+=a.x*b.w;
            acc[1][0]+=a.y*b.x; acc[1][1]+=a.y*b.y; acc[1][2]+=a.y*b.z; acc[1][3]+=a.y*b.w;
            acc[2][0]+=a.z*b.x; acc[2][1]+=a.z*b.y; acc[2][2]+=a.z*b.z; acc[2][3]+=a.z*b.w;
            acc[3][0]+=a.w*b.x; acc[3][1]+=a.w*b.y; acc[3][2]+=a.w*b.z; acc[3][3]+=a.w*b.w;
        }
        #pragma unroll
        for (int c = 0; c < 4; ++c) {
            int j = j0 + 4 * tc + c;
            float cn = cs[4 * tc + c];
            #pragma unroll
            for (int r = 0; r < 4; ++r) {
                float d = cn - 2.0f * acc[r][c];
                unsigned s = __float_as_uint(d);
                unsigned u = ((int)s < 0) ? ~s : (s | 0x80000000u);   // monotone float->uint
                unsigned long long p = ((unsigned long long)u << 32) | (unsigned)j;
                if (p < best[r]) best[r] = p;
            }
        }
    }

    #pragma unroll
    for (int r = 0; r < 4; ++r) pmin[(4 * tr + r) * 16 + tc] = best[r];
    __syncthreads();
    if (t < 64) {
        unsigned long long b = pmin[t * 16];
        #pragma unroll
        for (int q = 1; q < 16; ++q) {
            unsigned long long v = pmin[t * 16 + q];
            b = (v < b) ? v : b;
        }
        int j = (int)(unsigned)b;
        win[t] = j;
        int row = row0 + t;
        if (row < N_NODES) { a0[row] = j; atomicAdd(&cnt0[j], 1.0f); }
    }
    __syncthreads();
    // fused pooling: re-read x from LDS (As[lane][r]), wave w handles rows w*16..w*16+15
    int lane = t & 63, w = t >> 6;
    for (int rr = 0; rr < 16; ++rr) {
        int r = w * 16 + rr;
        int row = row0 + r;
        if (row >= N_NODES) break;
        int j = win[r];
        atomicAdd(&p0sum[j * FEA + lane], As[lane * 68 + r]);
    }
}

__global__ void pool_fin(float* __restrict__ psum, const float* __restrict__ cnt, int total) {
    int gid = blockIdx.x * 256 + threadIdx.x;
    if (gid < total) psum[gid] = psum[gid] / fmaxf(cnt[gid >> 6], 1.0f);
}

// ---------------- level-1: h1 = p0 @ W1, argmin vs C1, pool p0 -> p1 ----------------
__global__ __launch_bounds__(64) void level1(const float* __restrict__ p0, const float* __restrict__ W1,
                                             const float* __restrict__ C1, const float* __restrict__ c1n,
                                             int* __restrict__ a1, float* __restrict__ cnt1,
                                             float* __restrict__ p1sum) {
    int i = blockIdx.x;          // 1351 blocks, one wave each
    int lane = threadIdx.x;
    const float* pr = p0 + (size_t)i * FEA;
    float h[4] = {0.f, 0.f, 0.f, 0.f};
    for (int k = 0; k < FEA; ++k) {
        float pv = pr[k];                         // wave-uniform
        #pragma unroll
        for (int q = 0; q < 4; ++q) h[q] += pv * W1[k * HID + q * 64 + lane];
    }
    float hh = h[0]*h[0] + h[1]*h[1] + h[2]*h[2] + h[3]*h[3];
    for (int off = 32; off; off >>= 1) hh += __shfl_xor(hh, off);
    float best = 3.4e38f; int bj = 0;
    for (int j = 0; j < NP1; ++j) {
        const float* cj = C1 + j * HID;
        float dp = h[0]*cj[lane] + h[1]*cj[64+lane] + h[2]*cj[128+lane] + h[3]*cj[192+lane];
        for (int off = 32; off; off >>= 1) dp += __shfl_xor(dp, off);
        float d = hh - 2.0f * dp + c1n[j];
        if (d < best) { best = d; bj = j; }
    }
    if (lane == 0) { a1[i] = bj; atomicAdd(&cnt1[bj], 1.0f); }
    atomicAdd(&p1sum[bj * FEA + lane], pr[lane]);
}

// ---------------- level-2 (N2=1 => a2==0): p2 = mean(p1), corr2, g1sq, loss part 2 ----------------
__global__ __launch_bounds__(256) void level2(const float* __restrict__ p1, const float* __restrict__ fc,
                                              float* __restrict__ corr2, float* __restrict__ g1sq,
                                              float* __restrict__ loss2f) {
    __shared__ float p2s[64];
    __shared__ float lacc[64];
    int tid = threadIdx.x;
    if (tid < 64) {
        float s = 0.f;
        for (int i = 0; i < NP1; ++i) s += p1[i * FEA + tid];
        p2s[tid] = s * (1.0f / NP1);
        lacc[tid] = 0.f;
    }
    __syncthreads();
    for (int t = tid; t < NP1 * FEA; t += 256) {
        int f = t & 63;
        float dv = p1[t] - p2s[f];
        float c2 = dv * dv;
        corr2[t] = c2;
        float sg = 2.0f / (1.0f + __expf(-(fc[f] - c2)));
        g1sq[t] = sg * sg;
        atomicAdd(&lacc[f], c2);
    }
    __syncthreads();
    if (tid < 64) loss2f[tid] = lacc[tid] * (1.0f / NP1);
}

// ---------------- corr1, g0sq, loss part 1 ----------------
__global__ __launch_bounds__(256) void corr1_g0(const float* __restrict__ p0, const float* __restrict__ p1,
                                                const int* __restrict__ a1, const float* __restrict__ corr2,
                                                float* __restrict__ g0sq, float* __restrict__ loss1g) {
    __shared__ float sh[256];
    int tid = threadIdx.x;
    int f = tid & 63, sub = tid >> 6;
    int i = blockIdx.x * 4 + sub;
    float c1v = 0.f;
    if (i < NP0) {
        int a = a1[i];
        float dv = p0[i * FEA + f] - p1[a * FEA + f];
        c1v = dv * dv;
        float sg = 2.0f / (1.0f + __expf(-(corr2[a * FEA + f] - c1v)));
        g0sq[i * FEA + f] = sg * sg;
    }
    sh[tid] = c1v;
    __syncthreads();
    if (tid < 64) atomicAdd(&loss1g[tid], sh[tid] + sh[tid+64] + sh[tid+128] + sh[tid+192]);
}

__global__ void loss_final(const float* __restrict__ loss1g, const float* __restrict__ loss2f,
                           float* __restrict__ out_loss) {
    int lane = threadIdx.x;
    float v = loss1g[lane] * (1.0f / NP0) + loss2f[lane];
    for (int off = 32; off; off >>= 1) v += __shfl_xor(v, off);
    if (lane == 0) out_loss[0] = v * (1.0f / FEA) * 0.5f;   // /(NPOOL-1)
}

__global__ void cl1map(const int* __restrict__ a0, const int* __restrict__ a1, int* __restrict__ cl1) {
    int i = blockIdx.x * 256 + threadIdx.x;
    if (i < N_NODES) cl1[i] = a1[a0[i]];
}

// ---------------- fused per-row softmax + propagation, one wave per row ----------------
__global__ __launch_bounds__(256) void prop(const float* __restrict__ xin, const float* __restrict__ x0,
                                            const int* __restrict__ cols, const float* __restrict__ avals,
                                            const int* __restrict__ cl0, const int* __restrict__ cl1,
                                            const float* __restrict__ g0sq, const float* __restrict__ g1sq,
                                            float* __restrict__ xout) {
    int lane = threadIdx.x & 63;
    int i = blockIdx.x * 4 + __builtin_amdgcn_readfirstlane(threadIdx.x >> 6);
    int s0 = cl0[i], s1 = cl1[i];
    float g0f = g0sq[s0 * FEA + lane];
    float g1f = g1sq[s1 * FEA + lane];
    float x0f = x0[(size_t)i * FEA + lane];
    int ce[DEG]; float v[DEG];
    float m = -3.4e38f;
    #pragma unroll
    for (int e = 0; e < DEG; ++e) {
        int c = cols[i * DEG + e];
        ce[e] = c;
        float val = avals[i * DEG + e];
        if (cl0[c] == s0) val += g0f;
        if (cl1[c] == s1) val += g1f;
        v[e] = val;
        m = fmaxf(m, val);
    }
    float se = 0.f, acc = 0.f;
    #pragma unroll
    for (int e = 0; e < DEG; ++e) {
        float w = __expf(v[e] - m);
        se += w;
        acc += w * xin[(size_t)ce[e] * FEA + lane];
    }
    xout[(size_t)i * FEA + lane] = acc / se + x0f;   // ALPHA = 1
}

// ---------------- MLP layer 1: [x || x0] (K=128) @ mW1 + b, PReLU ----------------
__global__ __launch_bounds__(256) void mlp1(const float* __restrict__ xp, const float* __restrict__ x0,
                                            const float* __restrict__ W, const float* __restrict__ b,
                                            const float* __restrict__ pp, float* __restrict__ hout) {
    __shared__ float As[64 * 129];
    int bid = blockIdx.x;
    int rb = bid >> 2, cb = bid & 3;
    int row0 = rb * 64;
    int tid = threadIdx.x;
    for (int idx = tid; idx < 64 * 128; idx += 256) {
        int r = idx >> 7, k = idx & 127;
        int row = row0 + r;
        float vv = 0.f;
        if (row < N_NODES) vv = (k < 64) ? xp[(size_t)row * FEA + k] : x0[(size_t)row * FEA + (k - 64)];
        As[r * 129 + k] = vv;
    }
    __syncthreads();
    int r = tid & 63;
    int g = __builtin_amdgcn_readfirstlane(tid >> 6);
    int col0 = cb * 64 + g * 16;
    float acc[16];
    #pragma unroll
    for (int c = 0; c < 16; ++c) acc[c] = 0.f;
    for (int k = 0; k < 128; ++k) {
        float a = As[r * 129 + k];
        const float* w = W + k * HID + col0;   // wave-uniform -> scalar loads
        #pragma unroll
        for (int c = 0; c < 16; ++c) acc[c] += a * w[c];
    }
    int row = row0 + r;
    if (row < N_NODES) {
        float p = pp[0];
        float* o = hout + (size_t)row * HID + col0;
        #pragma unroll
        for (int c = 0; c < 16; ++c) {
            float h = acc[c] + b[col0 + c];
            o[c] = h >= 0.f ? h : p * h;
        }
    }
}

// ---------------- MLP layer 2: h1 (K=256) @ mW2 + b, PReLU ----------------
__global__ __launch_bounds__(256) void mlp2(const float* __restrict__ hin, const float* __restrict__ W,
                                            const float* __restrict__ b, const float* __restrict__ pp,
                                            float* __restrict__ hout) {
    __shared__ float As[64 * 129];
    int bid = blockIdx.x;
    int rb = bid >> 2, cb = bid & 3;
    int row0 = rb * 64;
    int tid = threadIdx.x;
    int r = tid & 63;
    int g = __builtin_amdgcn_readfirstlane(tid >> 6);
    int col0 = cb * 64 + g * 16;
    float acc[16];
    #pragma unroll
    for (int c = 0; c < 16; ++c) acc[c] = 0.f;
    for (int half = 0; half < 2; ++half) {
        __syncthreads();
        for (int idx = tid; idx < 64 * 128; idx += 256) {
            int rr = idx >> 7, k = idx & 127;
            int row = row0 + rr;
            As[rr * 129 + k] = (row < N_NODES) ? hin[(size_t)row * HID + half * 128 + k] : 0.f;
        }
        __syncthreads();
        for (int k = 0; k < 128; ++k) {
            float a = As[r * 129 + k];
            const float* w = W + (half * 128 + k) * HID + col0;
            #pragma unroll
            for (int c = 0; c < 16; ++c) acc[c] += a * w[c];
        }
    }
    int row = row0 + r;
    if (row < N_NODES) {
        float p = pp[0];
        float* o = hout + (size_t)row * HID + col0;
        #pragma unroll
        for (int c = 0; c < 16; ++c) {
            float h = acc[c] + b[col0 + c];
            o[c] = h >= 0.f ? h : p * h;
        }
    }
}

// ---------------- MLP layer 3 + log_softmax; lane = (row_sub, class) ----------------
__global__ __launch_bounds__(256) void mlp3(const float* __restrict__ hin, const float* __restrict__ W3,
                                            const float* __restrict__ b3, float* __restrict__ out) {
    __shared__ float Ws[HID * NCLS];
    int tid = threadIdx.x;
    for (int t = tid; t < HID * NCLS; t += 256) Ws[t] = W3[t];
    __syncthreads();
    int lane = tid & 63;
    int wv = __builtin_amdgcn_readfirstlane(tid >> 6);
    int rs = lane >> 4, c = lane & 15;
    int row = blockIdx.x * 16 + wv * 4 + rs;    // 3125 blocks * 16 rows = 50000 exactly
    const float4* hr = (const float4*)(hin + (size_t)row * HID);
    float acc = b3[c];
    for (int k4 = 0; k4 < 64; ++k4) {
        float4 h = hr[k4];
        int k = k4 * 4;
        acc += h.x * Ws[k * NCLS + c];
        acc += h.y * Ws[(k + 1) * NCLS + c];
        acc += h.z * Ws[(k + 2) * NCLS + c];
        acc += h.w * Ws[(k + 3) * NCLS + c];
    }
    float m = acc;
    #pragma unroll
    for (int off = 1; off < 16; off <<= 1) m = fmaxf(m, __shfl_xor(m, off));
    float e = __expf(acc - m);
    float s = e;
    #pragma unroll
    for (int off = 1; off < 16; off <<= 1) s += __shfl_xor(s, off);
    out[(size_t)row * NCLS + c] = acc - m - __logf(s);
}

extern "C" void kernel_launch(void* const* d_in, const int* in_sizes, int n_in,
                              void* d_out, int out_size, void* d_ws, size_t ws_size,
                              hipStream_t stream) {
    const float* x     = (const float*)d_in[0];
    const float* xcov  = (const float*)d_in[1];
    const float* avals = (const float*)d_in[2];
    const float* fc    = (const float*)d_in[3];
    const float* gamma = (const float*)d_in[4];
    const float* beta  = (const float*)d_in[5];
    const float* W0    = (const float*)d_in[6];
    const float* C0    = (const float*)d_in[7];
    const float* W1    = (const float*)d_in[8];
    const float* C1    = (const float*)d_in[9];
    // d_in[10], d_in[11] (W2, C2) only affect a2, which is argmin over 1 cluster -> always 0. Unused.
    const float* mW1   = (const float*)d_in[12];
    const float* mb1   = (const float*)d_in[13];
    const float* mp1   = (const float*)d_in[14];
    const float* mW2   = (const float*)d_in[15];
    const float* mb2   = (const float*)d_in[16];
    const float* mp2   = (const float*)d_in[17];
    const float* mW3   = (const float*)d_in[18];
    const float* mb3   = (const float*)d_in[19];
    // d_in[20] adj_rows == repeat(arange(N), 16) -> row of edge e is e>>4. Unused.
    const int* cols    = (const int*)d_in[21];

    float* ws = (float*)d_ws;
    size_t off = 0;
    auto alloc = [&](size_t n) { float* p = ws + off; off += (n + 63) & ~(size_t)63; return p; };

    float* x0    = alloc((size_t)N_NODES * FEA);
    float* h1b   = alloc((size_t)N_NODES * HID);   // xb1 aliases its head
    float* h2b   = alloc((size_t)N_NODES * HID);   // xb2 aliases its head
    float* W0t   = alloc(HID * FEA);
    float* Gt    = alloc((size_t)FEA * NP0T);
    float* c0n   = alloc(NP0T);
    float* c1n   = alloc(NP1);
    float* g0sq  = alloc(NP0 * FEA);
    float* g1sq  = alloc(NP1 * FEA);
    float* corr2 = alloc(NP1 * FEA);
    float* loss2f= alloc(64);
    int*   a0    = (int*)alloc(N_NODES);
    int*   cl1   = (int*)alloc(N_NODES);
    int*   a1    = (int*)alloc(NP0);
    // ---- zero-initialized block (single memset) ----
    float* zero0 = ws + off;
    float* bnsum = alloc(64);
    float* bnsq  = alloc(64);
    float* cnt0  = alloc(NP0);
    float* cnt1  = alloc(NP1);
    float* loss1g= alloc(64);
    float* p0    = alloc(NP0 * FEA);   // accumulated then finalized in place
    float* p1    = alloc(NP1 * FEA);
    size_t zbytes = (size_t)((ws + off) - zero0) * sizeof(float);

    float* xb1 = h1b;
    float* xb2 = h2b;
    float* outp = (float*)d_out;

    hipMemsetAsync(zero0, 0, zbytes, stream);

    bn_reduce<<<256, 256, 0, stream>>>(x, bnsum, bnsq);
    bn_apply<<<(N_NODES * FEA) / 256, 256, 0, stream>>>(x, bnsum, bnsq, gamma, beta, x0);

    transpose_W0<<<(FEA * HID + 255) / 256, 256, 0, stream>>>(W0, W0t);
    compute_G2<<<NP0T, 64, 0, stream>>>(W0t, C0, Gt, c0n);
    cnorm<<<NP1, 64, 0, stream>>>(C1, c1n);

    argmin0_gemm<<<(N_NODES + 63) / 64, 256, 0, stream>>>(xcov, Gt, c0n, a0, cnt0, p0);
    pool_fin<<<(NP0 * FEA + 255) / 256, 256, 0, stream>>>(p0, cnt0, NP0 * FEA);

    level1<<<NP0, 64, 0, stream>>>(p0, W1, C1, c1n, a1, cnt1, p1);
    pool_fin<<<(NP1 * FEA + 255) / 256, 256, 0, stream>>>(p1, cnt1, NP1 * FEA);

    level2<<<1, 256, 0, stream>>>(p1, fc, corr2, g1sq, loss2f);
    corr1_g0<<<(NP0 + 3) / 4, 256, 0, stream>>>(p0, p1, a1, corr2, g0sq, loss1g);
    loss_final<<<1, 64, 0, stream>>>(loss1g, loss2f, outp + (size_t)N_NODES * NCLS);

    cl1map<<<(N_NODES + 255) / 256, 256, 0, stream>>>(a0, a1, cl1);

    prop<<<N_NODES / 4, 256, 0, stream>>>(x0, x0, cols, avals, a0, cl1, g0sq, g1sq, xb1);
    prop<<<N_NODES / 4, 256, 0, stream>>>(xb1, x0, cols, avals, a0, cl1, g0sq, g1sq, xb2);

    int rowBlocks = (N_NODES + 63) / 64;
    mlp1<<<rowBlocks * 4, 256, 0, stream>>>(xb2, x0, mW1, mb1, mp1, h1b);
    mlp2<<<rowBlocks * 4, 256, 0, stream>>>(h1b, mW2, mb2, mp2, h2b);
    mlp3<<<N_NODES / 16, 256, 0, stream>>>(h2b, mW3, mb3, outp);
}